// Round 2
// baseline (254.586 us; speedup 1.0000x reference)
//
#include <hip/hip_runtime.h>

#define N_NODES 50000
#define DIM     128
#define N_EDGES 800000
#define N_LABEL 200000

// bucket partition: bucket = dst >> 6 (64 nodes/bucket), fixed capacity slots
#define NBUCK 782            // ceil(50000/64)
#define CAP   2048           // slots per bucket (mean fill ~1023, 32-sigma margin)
#define NPBLK 500            // partition blocks
#define CHUNK 1600           // edges per partition block

// src-range phasing: range = src >> RSH, NR ranges of 8192 nodes (2MB bf16 rows)
#define RSH 13
#define NR  7                // 50000 >> 13 = 6 -> ranges 0..6

// persistent aggregate grid: all blocks co-resident -> device-wide phase alignment
#define AGG_BLOCKS 1536
#define AGG_GROUPS (AGG_BLOCKS * 16)   // 24576 16-lane groups

typedef __attribute__((ext_vector_type(8)))  short short8;    // 8 bf16 (4 VGPRs)
typedef __attribute__((ext_vector_type(16))) float floatx16;  // 32x32 MFMA acc

// split fp32 into bf16 hi + bf16 lo (x ~= hi + lo, rel err ~2^-17), RNE both
__device__ inline void f32_to_bf16x2(float x, unsigned short& hi, unsigned short& lo) {
    unsigned u  = __float_as_uint(x);
    unsigned rh = (u + 0x7FFFu + ((u >> 16) & 1u)) >> 16;
    hi = (unsigned short)rh;
    float hif = __uint_as_float(rh << 16);
    float r = x - hif;
    unsigned ul = __float_as_uint(r);
    unsigned rl = (ul + 0x7FFFu + ((ul >> 16) & 1u)) >> 16;
    lo = (unsigned short)rl;
}

__device__ inline unsigned short f32_to_bf16(float x) {
    unsigned u = __float_as_uint(x);
    return (unsigned short)((u + 0x7FFFu + ((u >> 16) & 1u)) >> 16);
}

__device__ inline unsigned pack_bf16x2(float a, float b) {
    return (unsigned)f32_to_bf16(a) | ((unsigned)f32_to_bf16(b) << 16);
}

__device__ inline float bf_lo(unsigned u) { return __uint_as_float(u << 16); }
__device__ inline float bf_hi(unsigned u) { return __uint_as_float(u & 0xFFFF0000u); }

// fused: blocks [0,6250) build hb0 (bf16 only); [6250,6282) swizzle W; 6282 zeroes bcount
__global__ __launch_bounds__(256)
void build_h0_wf(const int* __restrict__ n_id,
                 const float* __restrict__ emb,
                 const float* __restrict__ xs,
                 unsigned* __restrict__ hb0,
                 const float* __restrict__ W1l, const float* __restrict__ W1r,
                 const float* __restrict__ W2l, const float* __restrict__ W2r,
                 unsigned short* __restrict__ WfH, unsigned short* __restrict__ WfL,
                 int* __restrict__ bcount) {
    if (blockIdx.x < 6250) {
        int t = blockIdx.x * 256 + threadIdx.x;     // < N_NODES*32 exactly
        int i = t >> 5, c = t & 31;
        float4 v;
        if (c < 16) {
            int nid = n_id[i];
            v = ((const float4*)emb)[nid * 16 + c];
        } else {
            v = ((const float4*)xs)[i * 16 + (c - 16)];
        }
        uint2 p;
        p.x = pack_bf16x2(v.x, v.y);
        p.y = pack_bf16x2(v.z, v.w);
        ((uint2*)hb0)[i * 32 + c] = p;
    } else if (blockIdx.x < 6282) {
        int t = (blockIdx.x - 6250) * 256 + threadIdx.x;   // 8192 chunks
        if (t >= 8192) return;
        int L  = t & 63;
        int nt = (t >> 6) & 3;
        int ks = (t >> 8) & 7;
        int p  = (t >> 11) & 1;
        int ly = t >> 12;
        const float* Ws[4] = {W1l, W1r, W2l, W2r};
        const float* W = Ws[ly * 2 + p];
        int n = nt * 32 + (L & 31);
        int kbase = ks * 16 + (L >> 5) * 8;
        short8 hv, lv;
#pragma unroll
        for (int j = 0; j < 8; ++j) {
            unsigned short hh, ll;
            f32_to_bf16x2(W[(kbase + j) * DIM + n], hh, ll);
            hv[j] = (short)hh;
            lv[j] = (short)ll;
        }
        *(short8*)(WfH + (size_t)t * 8) = hv;
        *(short8*)(WfL + (size_t)t * 8) = lv;
    } else {
        for (int i = threadIdx.x; i < NBUCK; i += 256) bcount[i] = 0;
    }
}

// fused hist + range-reserve + grouped scatter (no global scan).
// part record: src | (dst&63)<<16   (src < 2^16)
__global__ __launch_bounds__(256)
void part_scatter(const int* __restrict__ src, const int* __restrict__ dst,
                  int* __restrict__ bcount, unsigned* __restrict__ part) {
    __shared__ int hist[NBUCK];      // pass1: counts; pass2: write cursors
    int t = threadIdx.x;
    for (int i = t; i < NBUCK; i += 256) hist[i] = 0;
    __syncthreads();
    int base = blockIdx.x * CHUNK;
    for (int e = base + t; e < base + CHUNK; e += 256)
        atomicAdd(&hist[dst[e] >> 6], 1);
    __syncthreads();
    for (int i = t; i < NBUCK; i += 256) {
        int c = hist[i];
        hist[i] = c ? atomicAdd(&bcount[i], c) : 0;   // reserve [base, base+c)
    }
    __syncthreads();
    for (int e = base + t; e < base + CHUNK; e += 256) {
        int d = dst[e];
        int bk = d >> 6;
        int pos = atomicAdd(&hist[bk], 1);
        part[bk * CAP + pos] = (unsigned)src[e] | ((unsigned)(d & 63) << 16);
    }
}

// per-bucket: per-(node,range) hist + single-wave scan -> nro[node][0..7],
// then localized csr scatter grouped by (node, src-range) (ushort)
__global__ __launch_bounds__(256)
void bucket_csr(const unsigned* __restrict__ part, const int* __restrict__ bcount,
                int* __restrict__ nro, unsigned short* __restrict__ csr) {
    __shared__ int ldeg[64 * NR];
    __shared__ int lofs[64 * NR];
    __shared__ int lcur[64 * NR];
    int bk = blockIdx.x;
    int t = threadIdx.x;
    int cnt = bcount[bk];
    int base = bk * CAP;
    for (int i = t; i < 64 * NR; i += 256) ldeg[i] = 0;
    __syncthreads();
    for (int e = t; e < cnt; e += 256) {
        unsigned p = part[base + e];
        int key = (int)(p >> 16) * NR + (int)((p & 0xFFFFu) >> RSH);
        atomicAdd(&ldeg[key], 1);
    }
    __syncthreads();
    if (t < 64) {                     // one wave scans all 448 keys (7 chunks, carried)
        int carry = 0;
#pragma unroll
        for (int ch = 0; ch < NR; ++ch) {
            int k = ch * 64 + t;
            int v = ldeg[k];
            int s = v;
#pragma unroll
            for (int off = 1; off < 64; off <<= 1) {
                int u = __shfl_up(s, off, 64);
                if (t >= off) s += u;
            }
            lofs[k] = carry + s - v;          // exclusive prefix
            carry += __shfl(s, 63, 64);       // chunk total
        }
    }
    __syncthreads();
    // nro[node][r] = absolute csr start of (node, range r); [7] = node end
    for (int i = t; i < 64 * 8; i += 256) {
        int nl = i >> 3, r = i & 7;
        int node = bk * 64 + nl;
        if (node < N_NODES) {
            int v = (r < NR) ? (base + lofs[nl * NR + r])
                             : (base + lofs[nl * NR + NR - 1] + ldeg[nl * NR + NR - 1]);
            nro[node * 8 + r] = v;
        }
    }
    for (int i = t; i < 64 * NR; i += 256) lcur[i] = base + lofs[i];
    __syncthreads();
    for (int e = t; e < cnt; e += 256) {
        unsigned p = part[base + e];
        unsigned sv = p & 0xFFFFu;
        int key = (int)(p >> 16) * NR + (int)(sv >> RSH);
        int pos = atomicAdd(&lcur[key], 1);
        csr[pos] = (unsigned short)sv;
    }
}

// gather one (node, range) edge span into 8 accumulators (one uint4 slot per lane)
__device__ __forceinline__ void gather_range(int e0, int e1, int c, int hbase,
        const unsigned short* __restrict__ csr, const uint4* __restrict__ H,
        float (&a)[8]) {
    for (int b = e0; b < e1; b += 16) {
        int cnt = min(16, e1 - b);
        int idx = (b + c < e1) ? (int)csr[b + c] : 0;
        int j = 0;
        for (; j + 2 <= cnt; j += 2) {
            int m0 = __shfl(idx, hbase + j, 64);
            int m1 = __shfl(idx, hbase + j + 1, 64);
            uint4 v0 = H[(size_t)m0 * 16 + c];
            uint4 v1 = H[(size_t)m1 * 16 + c];
            a[0] += bf_lo(v0.x); a[1] += bf_hi(v0.x); a[2] += bf_lo(v0.y); a[3] += bf_hi(v0.y);
            a[4] += bf_lo(v0.z); a[5] += bf_hi(v0.z); a[6] += bf_lo(v0.w); a[7] += bf_hi(v0.w);
            a[0] += bf_lo(v1.x); a[1] += bf_hi(v1.x); a[2] += bf_lo(v1.y); a[3] += bf_hi(v1.y);
            a[4] += bf_lo(v1.z); a[5] += bf_hi(v1.z); a[6] += bf_lo(v1.w); a[7] += bf_hi(v1.w);
        }
        if (j < cnt) {
            int m0 = __shfl(idx, hbase + j, 64);
            uint4 v0 = H[(size_t)m0 * 16 + c];
            a[0] += bf_lo(v0.x); a[1] += bf_hi(v0.x); a[2] += bf_lo(v0.y); a[3] += bf_hi(v0.y);
            a[4] += bf_lo(v0.z); a[5] += bf_hi(v0.z); a[6] += bf_lo(v0.w); a[7] += bf_hi(v0.w);
        }
    }
}

__device__ __forceinline__ void store_mean(unsigned* __restrict__ aggb, int n, int c,
                                           int deg, const float (&a)[8]) {
    float rd = 1.0f / fmaxf((float)deg, 1.0f);
    uint4 o;
    o.x = pack_bf16x2(a[0] * rd, a[1] * rd);
    o.y = pack_bf16x2(a[2] * rd, a[3] * rd);
    o.z = pack_bf16x2(a[4] * rd, a[5] * rd);
    o.w = pack_bf16x2(a[6] * rd, a[7] * rd);
    ((uint4*)aggb)[(size_t)n * 16 + c] = o;
}

// persistent range-phased gather-mean: 16-lane group per node-pair, range loop
// OUTERMOST so all co-resident waves sweep the same 2MB src-slice together
// (per-XCD L2 fit). Lanes c<8 hold node0's nro[0..7], c in 8..15 hold node1's.
__global__ __launch_bounds__(256)
void aggregate_bf16(const int* __restrict__ nro,
                    const unsigned short* __restrict__ csr_src,
                    const unsigned* __restrict__ hb,
                    unsigned* __restrict__ aggb) {
    int gid  = blockIdx.x * 16 + (threadIdx.x >> 4);
    int lane = threadIdx.x & 63;
    int hbase = lane & 48;           // this group's lane base
    int c = lane & 15;               // uint4 slot within the 256B row
    int n0 = gid;
    int n1 = gid + AGG_GROUPS;
    int n2 = gid + 2 * AGG_GROUPS;   // rare third node (848 groups), unphased tail
    const uint4* H = (const uint4*)hb;

    int myofs = 0;
    {
        int nn = (c < 8) ? n0 : n1;
        if (nn < N_NODES) myofs = nro[nn * 8 + (c & 7)];
    }

    float a0[8] = {0.f, 0.f, 0.f, 0.f, 0.f, 0.f, 0.f, 0.f};
    float a1[8] = {0.f, 0.f, 0.f, 0.f, 0.f, 0.f, 0.f, 0.f};
#pragma unroll 1
    for (int r = 0; r < NR; ++r) {
        int e0 = __shfl(myofs, hbase + r, 64);
        int e1 = __shfl(myofs, hbase + r + 1, 64);
        gather_range(e0, e1, c, hbase, csr_src, H, a0);
        int f0 = __shfl(myofs, hbase + 8 + r, 64);
        int f1 = __shfl(myofs, hbase + 8 + r + 1, 64);
        gather_range(f0, f1, c, hbase, csr_src, H, a1);   // n1 invalid -> f0==f1==0, skipped
    }
    int d0 = __shfl(myofs, hbase + 7, 64) - __shfl(myofs, hbase, 64);
    store_mean(aggb, n0, c, d0, a0);
    if (n1 < N_NODES) {
        int d1 = __shfl(myofs, hbase + 15, 64) - __shfl(myofs, hbase + 8, 64);
        store_mean(aggb, n1, c, d1, a1);
    }
    if (n2 < N_NODES) {
        int e0 = nro[n2 * 8];
        int e1 = nro[n2 * 8 + 7];
#pragma unroll
        for (int i = 0; i < 8; ++i) a0[i] = 0.f;
        gather_range(e0, e1, c, hbase, csr_src, H, a0);
        store_mean(aggb, n2, c, e1 - e0, a0);
    }
}

// out = relu?( aggb@Wl + hb@Wr + b ); both A terms bf16-exact -> 2 MFMAs each (W hi/lo).
template <int RELU, int WRITE_F32, int WRITE_BF16>
__global__ __launch_bounds__(256)
void linear_mfma(const unsigned* __restrict__ aggb,
                 const unsigned* __restrict__ hbself,
                 const unsigned short* __restrict__ WfH,
                 const unsigned short* __restrict__ WfL,
                 const float* __restrict__ b,
                 float* __restrict__ out,
                 unsigned short* __restrict__ outb) {
    int tid  = threadIdx.x;
    int lane = tid & 63;
    int w    = tid >> 6;
    int row0 = blockIdx.x * 64 + (w & 1) * 32;
    int colhalf = w >> 1;
    int nt0 = colhalf * 2;
    int mc = min(row0 + (lane & 31), N_NODES - 1);
    int kh = lane >> 5;

    floatx16 acc0, acc1;
#pragma unroll
    for (int i = 0; i < 16; ++i) { acc0[i] = 0.f; acc1[i] = 0.f; }

    // A fragment for k-slice ks: bf16 elems ks*16+kh*8 .. +7 = uints ks*8+kh*4 .. +3
    const unsigned* arow = aggb   + (size_t)mc * 64 + kh * 4;
    const unsigned* hrow = hbself + (size_t)mc * 64 + kh * 4;

    // phase 0: agg term
#pragma unroll
    for (int ks = 0; ks < 8; ++ks) {
        short8 aa = *(const short8*)(arow + ks * 8);
        int cbase = (ks * 4 + nt0) * 64 + lane;
        short8 bh0 = *(const short8*)(WfH + (size_t)cbase * 8);
        short8 bl0 = *(const short8*)(WfL + (size_t)cbase * 8);
        short8 bh1 = *(const short8*)(WfH + (size_t)(cbase + 64) * 8);
        short8 bl1 = *(const short8*)(WfL + (size_t)(cbase + 64) * 8);
        acc0 = __builtin_amdgcn_mfma_f32_32x32x16_bf16(aa, bh0, acc0, 0, 0, 0);
        acc0 = __builtin_amdgcn_mfma_f32_32x32x16_bf16(aa, bl0, acc0, 0, 0, 0);
        acc1 = __builtin_amdgcn_mfma_f32_32x32x16_bf16(aa, bh1, acc1, 0, 0, 0);
        acc1 = __builtin_amdgcn_mfma_f32_32x32x16_bf16(aa, bl1, acc1, 0, 0, 0);
    }
    // phase 1: self term
#pragma unroll
    for (int ks = 0; ks < 8; ++ks) {
        short8 aa = *(const short8*)(hrow + ks * 8);
        int cbase = ((8 + ks) * 4 + nt0) * 64 + lane;
        short8 bh0 = *(const short8*)(WfH + (size_t)cbase * 8);
        short8 bl0 = *(const short8*)(WfL + (size_t)cbase * 8);
        short8 bh1 = *(const short8*)(WfH + (size_t)(cbase + 64) * 8);
        short8 bl1 = *(const short8*)(WfL + (size_t)(cbase + 64) * 8);
        acc0 = __builtin_amdgcn_mfma_f32_32x32x16_bf16(aa, bh0, acc0, 0, 0, 0);
        acc0 = __builtin_amdgcn_mfma_f32_32x32x16_bf16(aa, bl0, acc0, 0, 0, 0);
        acc1 = __builtin_amdgcn_mfma_f32_32x32x16_bf16(aa, bh1, acc1, 0, 0, 0);
        acc1 = __builtin_amdgcn_mfma_f32_32x32x16_bf16(aa, bl1, acc1, 0, 0, 0);
    }

    int col0 = colhalf * 64 + (lane & 31);
    float b0 = b[col0], b1 = b[col0 + 32];
#pragma unroll
    for (int reg = 0; reg < 16; ++reg) {
        int rloc = (reg & 3) + 8 * (reg >> 2) + 4 * kh;   // C/D row map (m74/m101)
        int rowg = row0 + rloc;
        if (rowg < N_NODES) {
            float v0 = acc0[reg] + b0;
            float v1 = acc1[reg] + b1;
            if (RELU) { v0 = fmaxf(v0, 0.f); v1 = fmaxf(v1, 0.f); }
            if (WRITE_F32) {
                out[(size_t)rowg * DIM + col0]      = v0;
                out[(size_t)rowg * DIM + col0 + 32] = v1;
            }
            if (WRITE_BF16) {
                outb[(size_t)rowg * DIM + col0]      = f32_to_bf16(v0);
                outb[(size_t)rowg * DIM + col0 + 32] = f32_to_bf16(v1);
            }
        }
    }
}

// logits from fp32 h2; 8 lanes/edge, 4xfloat4 per endpoint row (8 edges/wave, 16 rows in flight)
__global__ void edge_dot(const int* __restrict__ esrc, const int* __restrict__ edst,
                         const float* __restrict__ h2, float* __restrict__ out) {
    int t = blockIdx.x * blockDim.x + threadIdx.x;
    int e = t >> 3, c = t & 7;
    if (e >= N_LABEL) return;
    const float4* H = (const float4*)h2;
    int rs = esrc[e], rd = edst[e];
    float4 a0 = H[rs * 32 + 4 * c + 0];
    float4 a1 = H[rs * 32 + 4 * c + 1];
    float4 a2 = H[rs * 32 + 4 * c + 2];
    float4 a3 = H[rs * 32 + 4 * c + 3];
    float4 b0 = H[rd * 32 + 4 * c + 0];
    float4 b1 = H[rd * 32 + 4 * c + 1];
    float4 b2 = H[rd * 32 + 4 * c + 2];
    float4 b3 = H[rd * 32 + 4 * c + 3];
    float p = a0.x * b0.x + a0.y * b0.y + a0.z * b0.z + a0.w * b0.w
            + a1.x * b1.x + a1.y * b1.y + a1.z * b1.z + a1.w * b1.w
            + a2.x * b2.x + a2.y * b2.y + a2.z * b2.z + a2.w * b2.w
            + a3.x * b3.x + a3.y * b3.y + a3.z * b3.z + a3.w * b3.w;
#pragma unroll
    for (int off = 4; off; off >>= 1) p += __shfl_down(p, off, 8);
    if (c == 0) out[e] = p;
}

extern "C" void kernel_launch(void* const* d_in, const int* in_sizes, int n_in,
                              void* d_out, int out_size, void* d_ws, size_t ws_size,
                              hipStream_t stream) {
    const int*   n_id     = (const int*)d_in[0];
    const float* x_struct = (const float*)d_in[1];
    const int*   e_idx    = (const int*)d_in[2];   // [2, N_EDGES]
    const int*   eli      = (const int*)d_in[3];   // [2, N_LABEL]
    const float* emb      = (const float*)d_in[4];
    const float* W1l      = (const float*)d_in[5];
    const float* W1r      = (const float*)d_in[6];
    const float* b1       = (const float*)d_in[7];
    const float* W2l      = (const float*)d_in[8];
    const float* W2r      = (const float*)d_in[9];
    const float* b2       = (const float*)d_in[10];
    float* out = (float*)d_out;

    const int* src = e_idx;
    const int* dst = e_idx + N_EDGES;

    const size_t HN = (size_t)N_NODES * DIM;       // 6.4M elems
    float* h2     = (float*)d_ws;                  // fp32 (edge_dot accuracy)
    unsigned* aggb= (unsigned*)(h2 + HN);          // N_NODES*64 uints (bf16 agg)
    unsigned* hb0 = aggb + (size_t)N_NODES * 64;   // bf16 h0
    unsigned* hb1 = hb0 + (size_t)N_NODES * 64;    // bf16 h1
    int*   nro    = (int*)(hb1 + (size_t)N_NODES * 64);  // [N_NODES][8] range offsets
    int*   bcount = nro + (size_t)N_NODES * 8;     // NBUCK
    unsigned* part= (unsigned*)(bcount + NBUCK);   // NBUCK*CAP packed (src | local<<16)
    unsigned short* csr = (unsigned short*)(part + NBUCK * CAP);  // NBUCK*CAP ushort
    uintptr_t wa  = ((uintptr_t)(csr + NBUCK * CAP) + 15) & ~(uintptr_t)15;
    unsigned short* WfH = (unsigned short*)wa;     // 2*32768
    unsigned short* WfL = WfH + 2 * 32768;

    // build hb0 + W swizzle + bcount zero (bcount ready before part_scatter launches)
    build_h0_wf<<<6283, 256, 0, stream>>>(n_id, emb, x_struct, hb0,
                                          W1l, W1r, W2l, W2r, WfH, WfL, bcount);

    // CSR build: per-(node, src-range) sub-lists for phased gather
    part_scatter<<<NPBLK, 256, 0, stream>>>(src, dst, bcount, part);
    bucket_csr<<<NBUCK, 256, 0, stream>>>(part, bcount, nro, csr);

    // layer 1: bf16 h1 only (persistent range-phased aggregate)
    aggregate_bf16<<<AGG_BLOCKS, 256, 0, stream>>>(nro, csr, hb0, aggb);
    linear_mfma<1, 0, 1><<<(N_NODES + 63) / 64, 256, 0, stream>>>(
        aggb, hb0, WfH, WfL, b1, nullptr, (unsigned short*)hb1);

    // layer 2: fp32 h2 only (edge_dot reads fp32 for accuracy margin)
    aggregate_bf16<<<AGG_BLOCKS, 256, 0, stream>>>(nro, csr, hb1, aggb);
    linear_mfma<0, 1, 0><<<(N_NODES + 63) / 64, 256, 0, stream>>>(
        aggb, hb1, WfH + 32768, WfL + 32768, b2, h2, nullptr);

    edge_dot<<<(N_LABEL * 8 + 255) / 256, 256, 0, stream>>>(eli, eli + N_LABEL, h2, out);
}

// Round 3
// 235.023 us; speedup vs baseline: 1.0832x; 1.0832x over previous
//
#include <hip/hip_runtime.h>

#define N_NODES 50000
#define DIM     128
#define N_EDGES 800000
#define N_LABEL 200000

// bucket partition: bucket = dst >> 6 (64 nodes/bucket), fixed capacity slots
#define NBUCK 782            // ceil(50000/64)
#define CAP   2048           // slots per bucket (mean fill ~1023, 32-sigma margin)
#define NPBLK 250            // partition blocks
#define CHUNK 3200           // edges per partition block

typedef __attribute__((ext_vector_type(8)))  short short8;    // 8 bf16 (4 VGPRs)
typedef __attribute__((ext_vector_type(16))) float floatx16;  // 32x32 MFMA acc

// split fp32 into bf16 hi + bf16 lo (x ~= hi + lo, rel err ~2^-17), RNE both
__device__ inline void f32_to_bf16x2(float x, unsigned short& hi, unsigned short& lo) {
    unsigned u  = __float_as_uint(x);
    unsigned rh = (u + 0x7FFFu + ((u >> 16) & 1u)) >> 16;
    hi = (unsigned short)rh;
    float hif = __uint_as_float(rh << 16);
    float r = x - hif;
    unsigned ul = __float_as_uint(r);
    unsigned rl = (ul + 0x7FFFu + ((ul >> 16) & 1u)) >> 16;
    lo = (unsigned short)rl;
}

__device__ inline unsigned short f32_to_bf16(float x) {
    unsigned u = __float_as_uint(x);
    return (unsigned short)((u + 0x7FFFu + ((u >> 16) & 1u)) >> 16);
}

__device__ inline unsigned pack_bf16x2(float a, float b) {
    return (unsigned)f32_to_bf16(a) | ((unsigned)f32_to_bf16(b) << 16);
}

__device__ inline float bf_lo(unsigned u) { return __uint_as_float(u << 16); }
__device__ inline float bf_hi(unsigned u) { return __uint_as_float(u & 0xFFFF0000u); }

// fused: blocks [0,6250) build hb0 (bf16 only); [6250,6282) swizzle W; 6282 zeroes bcount
__global__ __launch_bounds__(256)
void build_h0_wf(const int* __restrict__ n_id,
                 const float* __restrict__ emb,
                 const float* __restrict__ xs,
                 unsigned* __restrict__ hb0,
                 const float* __restrict__ W1l, const float* __restrict__ W1r,
                 const float* __restrict__ W2l, const float* __restrict__ W2r,
                 unsigned short* __restrict__ WfH, unsigned short* __restrict__ WfL,
                 int* __restrict__ bcount) {
    if (blockIdx.x < 6250) {
        int t = blockIdx.x * 256 + threadIdx.x;     // < N_NODES*32 exactly
        int i = t >> 5, c = t & 31;
        float4 v;
        if (c < 16) {
            int nid = n_id[i];
            v = ((const float4*)emb)[nid * 16 + c];
        } else {
            v = ((const float4*)xs)[i * 16 + (c - 16)];
        }
        uint2 p;
        p.x = pack_bf16x2(v.x, v.y);
        p.y = pack_bf16x2(v.z, v.w);
        ((uint2*)hb0)[i * 32 + c] = p;
    } else if (blockIdx.x < 6282) {
        int t = (blockIdx.x - 6250) * 256 + threadIdx.x;   // 8192 chunks
        if (t >= 8192) return;
        int L  = t & 63;
        int nt = (t >> 6) & 3;
        int ks = (t >> 8) & 7;
        int p  = (t >> 11) & 1;
        int ly = t >> 12;
        const float* Ws[4] = {W1l, W1r, W2l, W2r};
        const float* W = Ws[ly * 2 + p];
        int n = nt * 32 + (L & 31);
        int kbase = ks * 16 + (L >> 5) * 8;
        short8 hv, lv;
#pragma unroll
        for (int j = 0; j < 8; ++j) {
            unsigned short hh, ll;
            f32_to_bf16x2(W[(kbase + j) * DIM + n], hh, ll);
            hv[j] = (short)hh;
            lv[j] = (short)ll;
        }
        *(short8*)(WfH + (size_t)t * 8) = hv;
        *(short8*)(WfL + (size_t)t * 8) = lv;
    } else {
        for (int i = threadIdx.x; i < NBUCK; i += 256) bcount[i] = 0;
    }
}

// fused hist + range-reserve + grouped scatter (no global scan).
// part record: src | (dst&63)<<16   (src < 2^16)
__global__ __launch_bounds__(256)
void part_scatter(const int* __restrict__ src, const int* __restrict__ dst,
                  int* __restrict__ bcount, unsigned* __restrict__ part) {
    __shared__ int hist[NBUCK];      // pass1: counts; pass2: write cursors
    int t = threadIdx.x;
    for (int i = t; i < NBUCK; i += 256) hist[i] = 0;
    __syncthreads();
    int base = blockIdx.x * CHUNK;
    for (int e = base + t; e < base + CHUNK; e += 256)
        atomicAdd(&hist[dst[e] >> 6], 1);
    __syncthreads();
    for (int i = t; i < NBUCK; i += 256) {
        int c = hist[i];
        hist[i] = c ? atomicAdd(&bcount[i], c) : 0;   // reserve [base, base+c)
    }
    __syncthreads();
    for (int e = base + t; e < base + CHUNK; e += 256) {
        int d = dst[e];
        int bk = d >> 6;
        int pos = atomicAdd(&hist[bk], 1);
        part[bk * CAP + pos] = (unsigned)src[e] | ((unsigned)(d & 63) << 16);
    }
}

// per-bucket: local deg + single-wave scan -> nbeg/nend, then localized csr scatter (ushort)
__global__ __launch_bounds__(256)
void bucket_csr(const unsigned* __restrict__ part, const int* __restrict__ bcount,
                int* __restrict__ nbeg, int* __restrict__ nend,
                unsigned short* __restrict__ csr) {
    __shared__ int ldeg[64];
    __shared__ int lcur[64];
    int bk = blockIdx.x;
    int t = threadIdx.x;
    int cnt = bcount[bk];
    int base = bk * CAP;
    if (t < 64) ldeg[t] = 0;
    __syncthreads();
    for (int e = t; e < cnt; e += 256)
        atomicAdd(&ldeg[part[base + e] >> 16], 1);
    __syncthreads();
    if (t < 64) {                     // one wave does the 64-wide scan
        int v = ldeg[t];
        int s = v;
#pragma unroll
        for (int off = 1; off < 64; off <<= 1) {
            int u = __shfl_up(s, off, 64);
            if (t >= off) s += u;
        }
        int excl = s - v;
        int node = bk * 64 + t;
        int b0 = base + excl;
        if (node < N_NODES) { nbeg[node] = b0; nend[node] = b0 + v; }
        lcur[t] = b0;
    }
    __syncthreads();
    for (int e = t; e < cnt; e += 256) {
        unsigned p = part[base + e];
        int pos = atomicAdd(&lcur[p >> 16], 1);
        csr[pos] = (unsigned short)(p & 0xFFFFu);
    }
}

#define ACCV(v) { a[0]+=bf_lo((v).x); a[1]+=bf_hi((v).x); a[2]+=bf_lo((v).y); a[3]+=bf_hi((v).y); \
                  a[4]+=bf_lo((v).z); a[5]+=bf_hi((v).z); a[6]+=bf_lo((v).w); a[7]+=bf_hi((v).w); }

// FUSED aggregate + linear for one 64-node tile (tile == csr bucket).
// Phase A: 16-lane groups gather-mean 4 nodes each into bf16 LDS tile
//          (slot XOR-swizzled by row so phase-B A-reads are <=4-way conflicted).
// Phase B: 32x32x16 MFMA: out = relu?( aggLDS@Wl + hsrc@Wr + b ).
template <int RELU, int WRITE_F32, int WRITE_BF16>
__global__ __launch_bounds__(256)
void fused_sage(const int* __restrict__ nbeg, const int* __restrict__ nend,
                const unsigned short* __restrict__ csr_src,
                const unsigned* __restrict__ hsrc,
                const unsigned short* __restrict__ WfH,
                const unsigned short* __restrict__ WfL,
                const float* __restrict__ b,
                float* __restrict__ out,
                unsigned short* __restrict__ outb) {
    __shared__ uint4 aggtile[64][16];     // 16KB bf16 agg tile, swizzled slots
    int tid  = threadIdx.x;
    int lane = tid & 63;
    int g    = tid >> 4;                  // 16-lane group id (0..15)
    int c    = tid & 15;                  // uint4 slot within 256B row
    int hbase = lane & 48;                // group's lane base within wave
    const uint4* H = (const uint4*)hsrc;

    // ---- phase A: aggregate 64 nodes (4 per group) ----
    for (int nn = 0; nn < 4; ++nn) {
        int nl = g + nn * 16;             // local row 0..63
        int node = blockIdx.x * 64 + nl;
        float a[8] = {0.f,0.f,0.f,0.f,0.f,0.f,0.f,0.f};
        int beg = 0, end = 0;
        if (node < N_NODES) { beg = nbeg[node]; end = nend[node]; }
        for (int bb = beg; bb < end; bb += 16) {
            int cnt = min(16, end - bb);
            int idx = (bb + c < end) ? (int)csr_src[bb + c] : 0;
            int j = 0;
            for (; j + 8 <= cnt; j += 8) {
                int n0 = __shfl(idx, hbase + j,     64);
                int n1 = __shfl(idx, hbase + j + 1, 64);
                int n2 = __shfl(idx, hbase + j + 2, 64);
                int n3 = __shfl(idx, hbase + j + 3, 64);
                int n4 = __shfl(idx, hbase + j + 4, 64);
                int n5 = __shfl(idx, hbase + j + 5, 64);
                int n6 = __shfl(idx, hbase + j + 6, 64);
                int n7 = __shfl(idx, hbase + j + 7, 64);
                uint4 v0 = H[n0 * 16 + c];
                uint4 v1 = H[n1 * 16 + c];
                uint4 v2 = H[n2 * 16 + c];
                uint4 v3 = H[n3 * 16 + c];
                uint4 v4 = H[n4 * 16 + c];
                uint4 v5 = H[n5 * 16 + c];
                uint4 v6 = H[n6 * 16 + c];
                uint4 v7 = H[n7 * 16 + c];
                ACCV(v0); ACCV(v1); ACCV(v2); ACCV(v3);
                ACCV(v4); ACCV(v5); ACCV(v6); ACCV(v7);
            }
            for (; j + 2 <= cnt; j += 2) {
                int n0 = __shfl(idx, hbase + j,     64);
                int n1 = __shfl(idx, hbase + j + 1, 64);
                uint4 v0 = H[n0 * 16 + c];
                uint4 v1 = H[n1 * 16 + c];
                ACCV(v0); ACCV(v1);
            }
            if (j < cnt) {
                int n0 = __shfl(idx, hbase + j, 64);
                uint4 v0 = H[n0 * 16 + c];
                ACCV(v0);
            }
        }
        float rd = 1.0f / fmaxf((float)(end - beg), 1.0f);
        uint4 o;
        o.x = pack_bf16x2(a[0] * rd, a[1] * rd);
        o.y = pack_bf16x2(a[2] * rd, a[3] * rd);
        o.z = pack_bf16x2(a[4] * rd, a[5] * rd);
        o.w = pack_bf16x2(a[6] * rd, a[7] * rd);
        aggtile[nl][c ^ (nl & 7)] = o;    // swizzled store (bijective per row)
    }
    __syncthreads();

    // ---- phase B: MFMA ----
    int w    = tid >> 6;
    int rh   = (w & 1) * 32;
    int row0 = blockIdx.x * 64 + rh;
    int colhalf = w >> 1;
    int nt0  = colhalf * 2;
    int ml   = rh + (lane & 31);          // local row 0..63 (always valid in LDS)
    int mc   = min(blockIdx.x * 64 + ml, N_NODES - 1);
    int kh   = lane >> 5;

    floatx16 acc0, acc1;
#pragma unroll
    for (int i = 0; i < 16; ++i) { acc0[i] = 0.f; acc1[i] = 0.f; }

    const unsigned* hrow = hsrc + (size_t)mc * 64 + kh * 4;

    // phase 0: agg term (A from LDS, slot kh+2*ks swizzled by row)
#pragma unroll
    for (int ks = 0; ks < 8; ++ks) {
        int slot = (kh + 2 * ks) ^ (ml & 7);
        short8 aa = *(const short8*)&aggtile[ml][slot];
        int cbase = (ks * 4 + nt0) * 64 + lane;
        short8 bh0 = *(const short8*)(WfH + (size_t)cbase * 8);
        short8 bl0 = *(const short8*)(WfL + (size_t)cbase * 8);
        short8 bh1 = *(const short8*)(WfH + (size_t)(cbase + 64) * 8);
        short8 bl1 = *(const short8*)(WfL + (size_t)(cbase + 64) * 8);
        acc0 = __builtin_amdgcn_mfma_f32_32x32x16_bf16(aa, bh0, acc0, 0, 0, 0);
        acc0 = __builtin_amdgcn_mfma_f32_32x32x16_bf16(aa, bl0, acc0, 0, 0, 0);
        acc1 = __builtin_amdgcn_mfma_f32_32x32x16_bf16(aa, bh1, acc1, 0, 0, 0);
        acc1 = __builtin_amdgcn_mfma_f32_32x32x16_bf16(aa, bl1, acc1, 0, 0, 0);
    }
    // phase 1: self term (A from global h rows)
#pragma unroll
    for (int ks = 0; ks < 8; ++ks) {
        short8 aa = *(const short8*)(hrow + ks * 8);
        int cbase = ((8 + ks) * 4 + nt0) * 64 + lane;
        short8 bh0 = *(const short8*)(WfH + (size_t)cbase * 8);
        short8 bl0 = *(const short8*)(WfL + (size_t)cbase * 8);
        short8 bh1 = *(const short8*)(WfH + (size_t)(cbase + 64) * 8);
        short8 bl1 = *(const short8*)(WfL + (size_t)(cbase + 64) * 8);
        acc0 = __builtin_amdgcn_mfma_f32_32x32x16_bf16(aa, bh0, acc0, 0, 0, 0);
        acc0 = __builtin_amdgcn_mfma_f32_32x32x16_bf16(aa, bl0, acc0, 0, 0, 0);
        acc1 = __builtin_amdgcn_mfma_f32_32x32x16_bf16(aa, bh1, acc1, 0, 0, 0);
        acc1 = __builtin_amdgcn_mfma_f32_32x32x16_bf16(aa, bl1, acc1, 0, 0, 0);
    }

    int col0 = colhalf * 64 + (lane & 31);
    float b0 = b[col0], b1 = b[col0 + 32];
#pragma unroll
    for (int reg = 0; reg < 16; ++reg) {
        int rloc = (reg & 3) + 8 * (reg >> 2) + 4 * kh;   // C/D row map (m74/m101)
        int rowg = row0 + rloc;
        if (rowg < N_NODES) {
            float v0 = acc0[reg] + b0;
            float v1 = acc1[reg] + b1;
            if (RELU) { v0 = fmaxf(v0, 0.f); v1 = fmaxf(v1, 0.f); }
            if (WRITE_F32) {
                out[(size_t)rowg * DIM + col0]      = v0;
                out[(size_t)rowg * DIM + col0 + 32] = v1;
            }
            if (WRITE_BF16) {
                outb[(size_t)rowg * DIM + col0]      = f32_to_bf16(v0);
                outb[(size_t)rowg * DIM + col0 + 32] = f32_to_bf16(v1);
            }
        }
    }
}

// logits from fp32 h2; 8 lanes/edge, 4xfloat4 per endpoint row (8 edges/wave, 16 rows in flight)
__global__ void edge_dot(const int* __restrict__ esrc, const int* __restrict__ edst,
                         const float* __restrict__ h2, float* __restrict__ out) {
    int t = blockIdx.x * blockDim.x + threadIdx.x;
    int e = t >> 3, c = t & 7;
    if (e >= N_LABEL) return;
    const float4* H = (const float4*)h2;
    int rs = esrc[e], rd = edst[e];
    float4 a0 = H[rs * 32 + 4 * c + 0];
    float4 a1 = H[rs * 32 + 4 * c + 1];
    float4 a2 = H[rs * 32 + 4 * c + 2];
    float4 a3 = H[rs * 32 + 4 * c + 3];
    float4 b0 = H[rd * 32 + 4 * c + 0];
    float4 b1 = H[rd * 32 + 4 * c + 1];
    float4 b2 = H[rd * 32 + 4 * c + 2];
    float4 b3 = H[rd * 32 + 4 * c + 3];
    float p = a0.x * b0.x + a0.y * b0.y + a0.z * b0.z + a0.w * b0.w
            + a1.x * b1.x + a1.y * b1.y + a1.z * b1.z + a1.w * b1.w
            + a2.x * b2.x + a2.y * b2.y + a2.z * b2.z + a2.w * b2.w
            + a3.x * b3.x + a3.y * b3.y + a3.z * b3.z + a3.w * b3.w;
#pragma unroll
    for (int off = 4; off; off >>= 1) p += __shfl_down(p, off, 8);
    if (c == 0) out[e] = p;
}

extern "C" void kernel_launch(void* const* d_in, const int* in_sizes, int n_in,
                              void* d_out, int out_size, void* d_ws, size_t ws_size,
                              hipStream_t stream) {
    const int*   n_id     = (const int*)d_in[0];
    const float* x_struct = (const float*)d_in[1];
    const int*   e_idx    = (const int*)d_in[2];   // [2, N_EDGES]
    const int*   eli      = (const int*)d_in[3];   // [2, N_LABEL]
    const float* emb      = (const float*)d_in[4];
    const float* W1l      = (const float*)d_in[5];
    const float* W1r      = (const float*)d_in[6];
    const float* b1       = (const float*)d_in[7];
    const float* W2l      = (const float*)d_in[8];
    const float* W2r      = (const float*)d_in[9];
    const float* b2       = (const float*)d_in[10];
    float* out = (float*)d_out;

    const int* src = e_idx;
    const int* dst = e_idx + N_EDGES;

    const size_t HN = (size_t)N_NODES * DIM;       // 6.4M elems
    float* h2     = (float*)d_ws;                  // fp32 (edge_dot accuracy)
    unsigned* hb0 = (unsigned*)(h2 + HN);          // bf16 h0
    unsigned* hb1 = hb0 + (size_t)N_NODES * 64;    // bf16 h1
    int*   nbeg   = (int*)(hb1 + (size_t)N_NODES * 64);
    int*   nend   = nbeg + N_NODES;
    int*   bcount = nend + N_NODES;                // NBUCK
    unsigned* part= (unsigned*)(bcount + NBUCK);   // NBUCK*CAP packed (src | local<<16)
    unsigned short* csr = (unsigned short*)(part + NBUCK * CAP);  // NBUCK*CAP ushort
    uintptr_t wa  = ((uintptr_t)(csr + NBUCK * CAP) + 15) & ~(uintptr_t)15;
    unsigned short* WfH = (unsigned short*)wa;     // 2*32768
    unsigned short* WfL = WfH + 2 * 32768;

    // build hb0 + W swizzle + bcount zero (bcount ready before part_scatter launches)
    build_h0_wf<<<6283, 256, 0, stream>>>(n_id, emb, x_struct, hb0,
                                          W1l, W1r, W2l, W2r, WfH, WfL, bcount);

    // CSR build: separate dispatches so the 250 heavy blocks get the whole device
    part_scatter<<<NPBLK, 256, 0, stream>>>(src, dst, bcount, part);
    bucket_csr<<<NBUCK, 256, 0, stream>>>(part, bcount, nbeg, nend, csr);

    // layer 1 (fused aggregate+linear): bf16 h1
    fused_sage<1, 0, 1><<<NBUCK, 256, 0, stream>>>(
        nbeg, nend, csr, hb0, WfH, WfL, b1, nullptr, (unsigned short*)hb1);

    // layer 2 (fused): fp32 h2 (edge_dot reads fp32 for accuracy margin)
    fused_sage<0, 1, 0><<<NBUCK, 256, 0, stream>>>(
        nbeg, nend, csr, hb1, WfH + 32768, WfL + 32768, b2, h2, nullptr);

    edge_dot<<<(N_LABEL * 8 + 255) / 256, 256, 0, stream>>>(eli, eli + N_LABEL, h2, out);
}

// Round 4
// 234.092 us; speedup vs baseline: 1.0875x; 1.0040x over previous
//
#include <hip/hip_runtime.h>

#define N_NODES 50000
#define DIM     128
#define N_EDGES 800000
#define N_LABEL 200000

// bucket partition: bucket = dst >> 5 (32 nodes/bucket), fixed capacity slots
#define NBUCK 1563           // ceil(50000/32)
#define CAP   1024           // slots per bucket (mean fill ~512, 22-sigma margin)
#define NPBLK 250            // partition blocks
#define CHUNK 3200           // edges per partition block

typedef __attribute__((ext_vector_type(8)))  short short8;    // 8 bf16 (4 VGPRs)
typedef __attribute__((ext_vector_type(16))) float floatx16;  // 32x32 MFMA acc

// split fp32 into bf16 hi + bf16 lo (x ~= hi + lo, rel err ~2^-17), RNE both
__device__ inline void f32_to_bf16x2(float x, unsigned short& hi, unsigned short& lo) {
    unsigned u  = __float_as_uint(x);
    unsigned rh = (u + 0x7FFFu + ((u >> 16) & 1u)) >> 16;
    hi = (unsigned short)rh;
    float hif = __uint_as_float(rh << 16);
    float r = x - hif;
    unsigned ul = __float_as_uint(r);
    unsigned rl = (ul + 0x7FFFu + ((ul >> 16) & 1u)) >> 16;
    lo = (unsigned short)rl;
}

__device__ inline unsigned short f32_to_bf16(float x) {
    unsigned u = __float_as_uint(x);
    return (unsigned short)((u + 0x7FFFu + ((u >> 16) & 1u)) >> 16);
}

__device__ inline unsigned pack_bf16x2(float a, float b) {
    return (unsigned)f32_to_bf16(a) | ((unsigned)f32_to_bf16(b) << 16);
}

__device__ inline float bf_lo(unsigned u) { return __uint_as_float(u << 16); }
__device__ inline float bf_hi(unsigned u) { return __uint_as_float(u & 0xFFFF0000u); }

// fused: blocks [0,6250) build hb0 (bf16 only); [6250,6282) swizzle W; 6282 zeroes bcount
__global__ __launch_bounds__(256)
void build_h0_wf(const int* __restrict__ n_id,
                 const float* __restrict__ emb,
                 const float* __restrict__ xs,
                 unsigned* __restrict__ hb0,
                 const float* __restrict__ W1l, const float* __restrict__ W1r,
                 const float* __restrict__ W2l, const float* __restrict__ W2r,
                 unsigned short* __restrict__ WfH, unsigned short* __restrict__ WfL,
                 int* __restrict__ bcount) {
    if (blockIdx.x < 6250) {
        int t = blockIdx.x * 256 + threadIdx.x;     // < N_NODES*32 exactly
        int i = t >> 5, c = t & 31;
        float4 v;
        if (c < 16) {
            int nid = n_id[i];
            v = ((const float4*)emb)[nid * 16 + c];
        } else {
            v = ((const float4*)xs)[i * 16 + (c - 16)];
        }
        uint2 p;
        p.x = pack_bf16x2(v.x, v.y);
        p.y = pack_bf16x2(v.z, v.w);
        ((uint2*)hb0)[i * 32 + c] = p;
    } else if (blockIdx.x < 6282) {
        int t = (blockIdx.x - 6250) * 256 + threadIdx.x;   // 8192 chunks
        if (t >= 8192) return;
        int L  = t & 63;
        int nt = (t >> 6) & 3;
        int ks = (t >> 8) & 7;
        int p  = (t >> 11) & 1;
        int ly = t >> 12;
        const float* Ws[4] = {W1l, W1r, W2l, W2r};
        const float* W = Ws[ly * 2 + p];
        int n = nt * 32 + (L & 31);
        int kbase = ks * 16 + (L >> 5) * 8;
        short8 hv, lv;
#pragma unroll
        for (int j = 0; j < 8; ++j) {
            unsigned short hh, ll;
            f32_to_bf16x2(W[(kbase + j) * DIM + n], hh, ll);
            hv[j] = (short)hh;
            lv[j] = (short)ll;
        }
        *(short8*)(WfH + (size_t)t * 8) = hv;
        *(short8*)(WfL + (size_t)t * 8) = lv;
    } else {
        for (int i = threadIdx.x; i < NBUCK; i += 256) bcount[i] = 0;
    }
}

// fused hist + range-reserve + grouped scatter (no global scan).
// part record: src | (dst&31)<<16   (src < 2^16)
__global__ __launch_bounds__(256)
void part_scatter(const int* __restrict__ src, const int* __restrict__ dst,
                  int* __restrict__ bcount, unsigned* __restrict__ part) {
    __shared__ int hist[NBUCK];      // pass1: counts; pass2: write cursors
    int t = threadIdx.x;
    for (int i = t; i < NBUCK; i += 256) hist[i] = 0;
    __syncthreads();
    int base = blockIdx.x * CHUNK;
    for (int e = base + t; e < base + CHUNK; e += 256)
        atomicAdd(&hist[dst[e] >> 5], 1);
    __syncthreads();
    for (int i = t; i < NBUCK; i += 256) {
        int c = hist[i];
        hist[i] = c ? atomicAdd(&bcount[i], c) : 0;   // reserve [base, base+c)
    }
    __syncthreads();
    for (int e = base + t; e < base + CHUNK; e += 256) {
        int d = dst[e];
        int bk = d >> 5;
        int pos = atomicAdd(&hist[bk], 1);
        part[bk * CAP + pos] = (unsigned)src[e] | ((unsigned)(d & 31) << 16);
    }
}

// per-bucket: local deg + 32-lane scan -> nbeg/nend, then localized csr scatter (ushort)
__global__ __launch_bounds__(256)
void bucket_csr(const unsigned* __restrict__ part, const int* __restrict__ bcount,
                int* __restrict__ nbeg, int* __restrict__ nend,
                unsigned short* __restrict__ csr) {
    __shared__ int ldeg[32];
    __shared__ int lcur[32];
    int bk = blockIdx.x;
    int t = threadIdx.x;
    int cnt = bcount[bk];
    int base = bk * CAP;
    if (t < 32) ldeg[t] = 0;
    __syncthreads();
    for (int e = t; e < cnt; e += 256)
        atomicAdd(&ldeg[part[base + e] >> 16], 1);
    __syncthreads();
    if (t < 32) {                     // 32-wide scan in wave 0
        int v = ldeg[t];
        int s = v;
#pragma unroll
        for (int off = 1; off < 32; off <<= 1) {
            int u = __shfl_up(s, off, 32);
            if (t >= off) s += u;
        }
        int excl = s - v;
        int node = bk * 32 + t;
        int b0 = base + excl;
        if (node < N_NODES) { nbeg[node] = b0; nend[node] = b0 + v; }
        lcur[t] = b0;
    }
    __syncthreads();
    for (int e = t; e < cnt; e += 256) {
        unsigned p = part[base + e];
        int pos = atomicAdd(&lcur[p >> 16], 1);
        csr[pos] = (unsigned short)(p & 0xFFFFu);
    }
}

#define ACCV(v) { a[0]+=bf_lo((v).x); a[1]+=bf_hi((v).x); a[2]+=bf_lo((v).y); a[3]+=bf_hi((v).y); \
                  a[4]+=bf_lo((v).z); a[5]+=bf_hi((v).z); a[6]+=bf_lo((v).w); a[7]+=bf_hi((v).w); }

// FUSED aggregate + linear for one 32-node tile (tile == csr bucket).
// Phase A: 16-lane groups gather-mean 2 nodes each into bf16 LDS tile
//          (slot XOR-swizzled by row so phase-B A-reads are <=4-way conflicted).
// Phase B: 4 waves, each owns one 32-col quarter of the 32x128 output:
//          out = relu?( aggLDS@Wl + hsrc@Wr + b ), 32x32x16 MFMA, K=128 each term.
template <int RELU, int WRITE_F32, int WRITE_BF16>
__global__ __launch_bounds__(256)
void fused_sage(const int* __restrict__ nbeg, const int* __restrict__ nend,
                const unsigned short* __restrict__ csr_src,
                const unsigned* __restrict__ hsrc,
                const unsigned short* __restrict__ WfH,
                const unsigned short* __restrict__ WfL,
                const float* __restrict__ b,
                float* __restrict__ out,
                unsigned short* __restrict__ outb) {
    __shared__ uint4 aggtile[32][16];     // 8KB bf16 agg tile, swizzled slots
    int tid  = threadIdx.x;
    int lane = tid & 63;
    int g    = tid >> 4;                  // 16-lane group id (0..15)
    int c    = tid & 15;                  // uint4 slot within 256B row
    int hbase = lane & 48;                // group's lane base within wave
    const uint4* H = (const uint4*)hsrc;

    // ---- phase A: aggregate 32 nodes (2 per group) ----
    for (int nn = 0; nn < 2; ++nn) {
        int nl = g + nn * 16;             // local row 0..31
        int node = blockIdx.x * 32 + nl;
        float a[8] = {0.f,0.f,0.f,0.f,0.f,0.f,0.f,0.f};
        int beg = 0, end = 0;
        if (node < N_NODES) { beg = nbeg[node]; end = nend[node]; }
        for (int bb = beg; bb < end; bb += 16) {
            int cnt = min(16, end - bb);
            int idx = (bb + c < end) ? (int)csr_src[bb + c] : 0;
            int j = 0;
            for (; j + 8 <= cnt; j += 8) {
                int n0 = __shfl(idx, hbase + j,     64);
                int n1 = __shfl(idx, hbase + j + 1, 64);
                int n2 = __shfl(idx, hbase + j + 2, 64);
                int n3 = __shfl(idx, hbase + j + 3, 64);
                int n4 = __shfl(idx, hbase + j + 4, 64);
                int n5 = __shfl(idx, hbase + j + 5, 64);
                int n6 = __shfl(idx, hbase + j + 6, 64);
                int n7 = __shfl(idx, hbase + j + 7, 64);
                uint4 v0 = H[n0 * 16 + c];
                uint4 v1 = H[n1 * 16 + c];
                uint4 v2 = H[n2 * 16 + c];
                uint4 v3 = H[n3 * 16 + c];
                uint4 v4 = H[n4 * 16 + c];
                uint4 v5 = H[n5 * 16 + c];
                uint4 v6 = H[n6 * 16 + c];
                uint4 v7 = H[n7 * 16 + c];
                ACCV(v0); ACCV(v1); ACCV(v2); ACCV(v3);
                ACCV(v4); ACCV(v5); ACCV(v6); ACCV(v7);
            }
            for (; j + 2 <= cnt; j += 2) {
                int n0 = __shfl(idx, hbase + j,     64);
                int n1 = __shfl(idx, hbase + j + 1, 64);
                uint4 v0 = H[n0 * 16 + c];
                uint4 v1 = H[n1 * 16 + c];
                ACCV(v0); ACCV(v1);
            }
            if (j < cnt) {
                int n0 = __shfl(idx, hbase + j, 64);
                uint4 v0 = H[n0 * 16 + c];
                ACCV(v0);
            }
        }
        float rd = 1.0f / fmaxf((float)(end - beg), 1.0f);
        uint4 o;
        o.x = pack_bf16x2(a[0] * rd, a[1] * rd);
        o.y = pack_bf16x2(a[2] * rd, a[3] * rd);
        o.z = pack_bf16x2(a[4] * rd, a[5] * rd);
        o.w = pack_bf16x2(a[6] * rd, a[7] * rd);
        aggtile[nl][c ^ (nl & 7)] = o;    // swizzled store (bijective per row)
    }
    __syncthreads();

    // ---- phase B: MFMA, wave w owns cols [w*32, w*32+32) ----
    int w    = tid >> 6;                  // col-tile index 0..3
    int ml   = lane & 31;                 // local row 0..31
    int mc   = min(blockIdx.x * 32 + ml, N_NODES - 1);
    int kh   = lane >> 5;

    floatx16 acc;
#pragma unroll
    for (int i = 0; i < 16; ++i) acc[i] = 0.f;

    const unsigned* hrow = hsrc + (size_t)mc * 64 + kh * 4;

    // agg term (A from LDS, slot kh+2*ks swizzled by row)
#pragma unroll
    for (int ks = 0; ks < 8; ++ks) {
        int slot = (kh + 2 * ks) ^ (ml & 7);
        short8 aa = *(const short8*)&aggtile[ml][slot];
        int cbase = (ks * 4 + w) * 64 + lane;
        short8 bh = *(const short8*)(WfH + (size_t)cbase * 8);
        short8 bl = *(const short8*)(WfL + (size_t)cbase * 8);
        acc = __builtin_amdgcn_mfma_f32_32x32x16_bf16(aa, bh, acc, 0, 0, 0);
        acc = __builtin_amdgcn_mfma_f32_32x32x16_bf16(aa, bl, acc, 0, 0, 0);
    }
    // self term (A from global h rows)
#pragma unroll
    for (int ks = 0; ks < 8; ++ks) {
        short8 aa = *(const short8*)(hrow + ks * 8);
        int cbase = ((8 + ks) * 4 + w) * 64 + lane;
        short8 bh = *(const short8*)(WfH + (size_t)cbase * 8);
        short8 bl = *(const short8*)(WfL + (size_t)cbase * 8);
        acc = __builtin_amdgcn_mfma_f32_32x32x16_bf16(aa, bh, acc, 0, 0, 0);
        acc = __builtin_amdgcn_mfma_f32_32x32x16_bf16(aa, bl, acc, 0, 0, 0);
    }

    int col0 = w * 32 + (lane & 31);
    float bb = b[col0];
#pragma unroll
    for (int reg = 0; reg < 16; ++reg) {
        int rloc = (reg & 3) + 8 * (reg >> 2) + 4 * kh;   // C/D row map (m74/m101)
        int rowg = blockIdx.x * 32 + rloc;
        if (rowg < N_NODES) {
            float v0 = acc[reg] + bb;
            if (RELU) v0 = fmaxf(v0, 0.f);
            if (WRITE_F32)  out[(size_t)rowg * DIM + col0]  = v0;
            if (WRITE_BF16) outb[(size_t)rowg * DIM + col0] = f32_to_bf16(v0);
        }
    }
}

// logits from bf16 h2; 8 lanes/edge, 2xuint4 (16 bf16) per endpoint row
__global__ void edge_dot(const int* __restrict__ esrc, const int* __restrict__ edst,
                         const unsigned* __restrict__ h2b, float* __restrict__ out) {
    int t = blockIdx.x * blockDim.x + threadIdx.x;
    int e = t >> 3, c = t & 7;
    if (e >= N_LABEL) return;
    const uint4* H = (const uint4*)h2b;
    int rs = esrc[e], rd = edst[e];
    uint4 a0 = H[rs * 16 + 2 * c + 0];
    uint4 a1 = H[rs * 16 + 2 * c + 1];
    uint4 b0 = H[rd * 16 + 2 * c + 0];
    uint4 b1 = H[rd * 16 + 2 * c + 1];
    float p = bf_lo(a0.x) * bf_lo(b0.x) + bf_hi(a0.x) * bf_hi(b0.x)
            + bf_lo(a0.y) * bf_lo(b0.y) + bf_hi(a0.y) * bf_hi(b0.y)
            + bf_lo(a0.z) * bf_lo(b0.z) + bf_hi(a0.z) * bf_hi(b0.z)
            + bf_lo(a0.w) * bf_lo(b0.w) + bf_hi(a0.w) * bf_hi(b0.w)
            + bf_lo(a1.x) * bf_lo(b1.x) + bf_hi(a1.x) * bf_hi(b1.x)
            + bf_lo(a1.y) * bf_lo(b1.y) + bf_hi(a1.y) * bf_hi(b1.y)
            + bf_lo(a1.z) * bf_lo(b1.z) + bf_hi(a1.z) * bf_hi(b1.z)
            + bf_lo(a1.w) * bf_lo(b1.w) + bf_hi(a1.w) * bf_hi(b1.w);
#pragma unroll
    for (int off = 4; off; off >>= 1) p += __shfl_down(p, off, 8);
    if (c == 0) out[e] = p;
}

extern "C" void kernel_launch(void* const* d_in, const int* in_sizes, int n_in,
                              void* d_out, int out_size, void* d_ws, size_t ws_size,
                              hipStream_t stream) {
    const int*   n_id     = (const int*)d_in[0];
    const float* x_struct = (const float*)d_in[1];
    const int*   e_idx    = (const int*)d_in[2];   // [2, N_EDGES]
    const int*   eli      = (const int*)d_in[3];   // [2, N_LABEL]
    const float* emb      = (const float*)d_in[4];
    const float* W1l      = (const float*)d_in[5];
    const float* W1r      = (const float*)d_in[6];
    const float* b1       = (const float*)d_in[7];
    const float* W2l      = (const float*)d_in[8];
    const float* W2r      = (const float*)d_in[9];
    const float* b2       = (const float*)d_in[10];
    float* out = (float*)d_out;

    const int* src = e_idx;
    const int* dst = e_idx + N_EDGES;

    unsigned* hb2 = (unsigned*)d_ws;               // bf16 h2 (edge_dot input)
    unsigned* hb0 = hb2 + (size_t)N_NODES * 64;    // bf16 h0
    unsigned* hb1 = hb0 + (size_t)N_NODES * 64;    // bf16 h1
    int*   nbeg   = (int*)(hb1 + (size_t)N_NODES * 64);
    int*   nend   = nbeg + N_NODES;
    int*   bcount = nend + N_NODES;                // NBUCK
    unsigned* part= (unsigned*)(bcount + NBUCK);   // NBUCK*CAP packed (src | local<<16)
    unsigned short* csr = (unsigned short*)(part + (size_t)NBUCK * CAP);  // NBUCK*CAP ushort
    uintptr_t wa  = ((uintptr_t)(csr + (size_t)NBUCK * CAP) + 15) & ~(uintptr_t)15;
    unsigned short* WfH = (unsigned short*)wa;     // 2*32768
    unsigned short* WfL = WfH + 2 * 32768;

    // build hb0 + W swizzle + bcount zero (bcount ready before part_scatter launches)
    build_h0_wf<<<6283, 256, 0, stream>>>(n_id, emb, x_struct, hb0,
                                          W1l, W1r, W2l, W2r, WfH, WfL, bcount);

    // CSR build: separate dispatches so the 250 heavy blocks get the whole device
    part_scatter<<<NPBLK, 256, 0, stream>>>(src, dst, bcount, part);
    bucket_csr<<<NBUCK, 256, 0, stream>>>(part, bcount, nbeg, nend, csr);

    // layer 1 (fused aggregate+linear): bf16 h1
    fused_sage<1, 0, 1><<<NBUCK, 256, 0, stream>>>(
        nbeg, nend, csr, hb0, WfH, WfL, b1, nullptr, (unsigned short*)hb1);

    // layer 2 (fused): bf16 h2 (edge_dot gathers 256B rows instead of 512B fp32)
    fused_sage<0, 0, 1><<<NBUCK, 256, 0, stream>>>(
        nbeg, nend, csr, hb1, WfH + 32768, WfL + 32768, b2, nullptr, (unsigned short*)hb2);

    edge_dot<<<(N_LABEL * 8 + 255) / 256, 256, 0, stream>>>(eli, eli + N_LABEL, hb2, out);
}